// Round 1
// baseline (2004.469 us; speedup 1.0000x reference)
//
#include <hip/hip_runtime.h>
#include <hip/hip_bf16.h>

// GCN forward: out = spmm(A, relu(spmm(A, x@W1)+b1) @ W2) + b2
// N=50000, F=512, H=128, C=40, E=800000

#define NFEAT 512
#define NHID  128
#define NCLS  40

// ---------------- GEMM1: support[N,128] = x[N,512] @ W1[512,128] ----------------
// Tile: BM=64 rows x BN=128 cols, BK=32. 256 threads, each computes 4x8 micro-tile.
__global__ __launch_bounds__(256) void gemm1_kernel(
    const float* __restrict__ x, const float* __restrict__ W1,
    float* __restrict__ support, int nrows) {
  __shared__ float sx[64][33];    // +1 pad: A-reads hit 4 distinct banks
  __shared__ float sw[32][132];   // +4 pad keeps float4 alignment, spreads banks
  const int tid = threadIdx.x;
  const int tx = tid & 15;        // col group (8 cols each)
  const int ty = tid >> 4;        // row group (4 rows each)
  const int row0 = blockIdx.x * 64;

  float acc[4][8];
#pragma unroll
  for (int i = 0; i < 4; ++i)
#pragma unroll
    for (int j = 0; j < 8; ++j) acc[i][j] = 0.f;

  for (int k0 = 0; k0 < NFEAT; k0 += 32) {
    // load x tile: 64x32 floats = 512 float4, 2 per thread
#pragma unroll
    for (int i = 0; i < 2; ++i) {
      int f = tid + 256 * i;            // float4 idx
      int r = f >> 3, c = (f & 7) << 2;
      float4 v = make_float4(0.f, 0.f, 0.f, 0.f);
      int gr = row0 + r;
      if (gr < nrows) v = *(const float4*)&x[(size_t)gr * NFEAT + k0 + c];
      sx[r][c] = v.x; sx[r][c + 1] = v.y; sx[r][c + 2] = v.z; sx[r][c + 3] = v.w;
    }
    // load W1 tile: 32x128 floats = 1024 float4, 4 per thread
#pragma unroll
    for (int i = 0; i < 4; ++i) {
      int f = tid + 256 * i;
      int r = f >> 5, c = (f & 31) << 2;
      float4 v = *(const float4*)&W1[(size_t)(k0 + r) * NHID + c];
      sw[r][c] = v.x; sw[r][c + 1] = v.y; sw[r][c + 2] = v.z; sw[r][c + 3] = v.w;
    }
    __syncthreads();
#pragma unroll
    for (int kk = 0; kk < 32; ++kk) {
      float a[4];
#pragma unroll
      for (int i = 0; i < 4; ++i) a[i] = sx[ty * 4 + i][kk];  // broadcast reads
      float4 b0 = *(const float4*)&sw[kk][tx * 8];
      float4 b1v = *(const float4*)&sw[kk][tx * 8 + 4];
      float b[8] = {b0.x, b0.y, b0.z, b0.w, b1v.x, b1v.y, b1v.z, b1v.w};
#pragma unroll
      for (int i = 0; i < 4; ++i)
#pragma unroll
        for (int j = 0; j < 8; ++j) acc[i][j] += a[i] * b[j];
    }
    __syncthreads();
  }
#pragma unroll
  for (int i = 0; i < 4; ++i) {
    int gr = row0 + ty * 4 + i;
    if (gr < nrows) {
      float4 v0 = make_float4(acc[i][0], acc[i][1], acc[i][2], acc[i][3]);
      float4 v1 = make_float4(acc[i][4], acc[i][5], acc[i][6], acc[i][7]);
      *(float4*)&support[(size_t)gr * NHID + tx * 8] = v0;
      *(float4*)&support[(size_t)gr * NHID + tx * 8 + 4] = v1;
    }
  }
}

// ---------------- SpMM1: h[dst] += w * support[src], 128 feats -----------------
// one thread per (edge, feat-quad): 32 quads of float4 per edge
__global__ __launch_bounds__(256) void spmm1_kernel(
    const int* __restrict__ esrc, const int* __restrict__ edst,
    const float* __restrict__ ew, const float* __restrict__ support,
    float* __restrict__ h, int E) {
  int idx = blockIdx.x * 256 + threadIdx.x;
  int e = idx >> 5, q = idx & 31;
  if (e >= E) return;
  int s = esrc[e], d = edst[e];
  float w = ew[e];
  float4 v = ((const float4*)support)[(size_t)s * 32 + q];
  float* o = &h[(size_t)d * NHID + q * 4];
  atomicAdd(o + 0, w * v.x);
  atomicAdd(o + 1, w * v.y);
  atomicAdd(o + 2, w * v.z);
  atomicAdd(o + 3, w * v.w);
}

// ------- GEMM2: s2[N,40] = relu(h+b1) @ W2[128,40], bias+relu fused on load ------
__global__ __launch_bounds__(256) void gemm2_kernel(
    const float* __restrict__ h, const float* __restrict__ b1,
    const float* __restrict__ W2, float* __restrict__ s2, int nrows) {
  __shared__ float sh[32][128];
  __shared__ float swt[128][40];
  __shared__ float sb[128];
  const int tid = threadIdx.x;
  if (tid < 128) sb[tid] = b1[tid];
  for (int i = tid; i < 128 * 40; i += 256) swt[i / 40][i % 40] = W2[i];
  __syncthreads();
  const int row0 = blockIdx.x * 32;
#pragma unroll
  for (int i = 0; i < 4; ++i) {
    int f = tid + 256 * i;            // float4 idx over 32x128 tile
    int r = f >> 5, c = (f & 31) << 2;
    int gr = row0 + r;
    float4 v = make_float4(0.f, 0.f, 0.f, 0.f);
    if (gr < nrows) v = *(const float4*)&h[(size_t)gr * NHID + c];
    sh[r][c]     = fmaxf(v.x + sb[c], 0.f);
    sh[r][c + 1] = fmaxf(v.y + sb[c + 1], 0.f);
    sh[r][c + 2] = fmaxf(v.z + sb[c + 2], 0.f);
    sh[r][c + 3] = fmaxf(v.w + sb[c + 3], 0.f);
  }
  __syncthreads();
#pragma unroll
  for (int j = 0; j < 5; ++j) {
    int o = tid + 256 * j;            // 0..1279 = 32 rows x 40 cols
    int r = o / 40, c = o % 40;
    float acc = 0.f;
#pragma unroll 8
    for (int k = 0; k < 128; ++k) acc += sh[r][k] * swt[k][c];
    int gr = row0 + r;
    if (gr < nrows) s2[(size_t)gr * NCLS + c] = acc;
  }
}

// ---------------- init out with bias b2 ----------------
__global__ __launch_bounds__(256) void init_out_kernel(
    float* __restrict__ out, const float* __restrict__ b2, long long total) {
  long long i = (long long)blockIdx.x * 256 + threadIdx.x;
  if (i < total) out[i] = b2[i % NCLS];
}

// ---------------- SpMM2: out[dst] += w * s2[src], 40 feats ----------------
// 16 threads per edge, first 10 handle one float4 each
__global__ __launch_bounds__(256) void spmm2_kernel(
    const int* __restrict__ esrc, const int* __restrict__ edst,
    const float* __restrict__ ew, const float* __restrict__ s2,
    float* __restrict__ out, int E) {
  int idx = blockIdx.x * 256 + threadIdx.x;
  int e = idx >> 4, t = idx & 15;
  if (e >= E || t >= 10) return;
  int s = esrc[e], d = edst[e];
  float w = ew[e];
  float4 v = ((const float4*)s2)[(size_t)s * 10 + t];
  float* o = &out[(size_t)d * NCLS + t * 4];
  atomicAdd(o + 0, w * v.x);
  atomicAdd(o + 1, w * v.y);
  atomicAdd(o + 2, w * v.z);
  atomicAdd(o + 3, w * v.w);
}

extern "C" void kernel_launch(void* const* d_in, const int* in_sizes, int n_in,
                              void* d_out, int out_size, void* d_ws, size_t ws_size,
                              hipStream_t stream) {
  const float* x   = (const float*)d_in[0];
  const float* W1  = (const float*)d_in[1];
  const float* b1  = (const float*)d_in[2];
  const float* W2  = (const float*)d_in[3];
  const float* b2  = (const float*)d_in[4];
  const int* esrc  = (const int*)d_in[5];
  const int* edst  = (const int*)d_in[6];
  const float* ew  = (const float*)d_in[7];
  float* out = (float*)d_out;

  const int N = in_sizes[0] / NFEAT;   // 50000
  const int E = in_sizes[5];           // 800000

  char* ws = (char*)d_ws;
  float* support = (float*)ws;                                  // N*128 f32
  float* h       = (float*)(ws + (size_t)N * NHID * 4);          // N*128 f32
  float* s2      = (float*)(ws + (size_t)N * NHID * 8);          // N*40  f32

  // h accumulates via atomics -> zero it every call (replay-safe)
  hipMemsetAsync(h, 0, (size_t)N * NHID * 4, stream);

  gemm1_kernel<<<(N + 63) / 64, 256, 0, stream>>>(x, W1, support, N);
  spmm1_kernel<<<(E * 32 + 255) / 256, 256, 0, stream>>>(esrc, edst, ew, support, h, E);
  gemm2_kernel<<<(N + 31) / 32, 256, 0, stream>>>(h, b1, W2, s2, N);

  long long total_out = (long long)N * NCLS;
  init_out_kernel<<<(int)((total_out + 255) / 256), 256, 0, stream>>>(out, b2, total_out);
  spmm2_kernel<<<(E * 16 + 255) / 256, 256, 0, stream>>>(esrc, edst, ew, s2, out, E);
}

// Round 2
// 474.109 us; speedup vs baseline: 4.2279x; 4.2279x over previous
//
#include <hip/hip_runtime.h>
#include <hip/hip_bf16.h>

// GCN forward: out = spmm(A, relu(spmm(A, x@W1)+b1) @ W2) + b2
// N=50000, F=512, H=128, C=40, E=800000
// Strategy: build CSR-by-dst on device (int atomics only), then gather-form SpMM
// (zero fp32 atomics, each output row written exactly once).

#define NFEAT 512
#define NHID  128
#define NCLS  40

// ---------------- CSR build ----------------
__global__ __launch_bounds__(256) void hist_kernel(
    const int* __restrict__ edst, int* __restrict__ deg, int E) {
  int e = blockIdx.x * 256 + threadIdx.x;
  if (e < E) atomicAdd(&deg[edst[e]], 1);
}

// single-block exclusive scan over deg[0..n) -> offs[0..n], offs[n]=total
__global__ __launch_bounds__(1024) void scan_kernel(
    const int* __restrict__ deg, int* __restrict__ offs, int n) {
  __shared__ int part[1024];
  const int tid = threadIdx.x;
  const int per = (n + 1023) / 1024;
  const int base = tid * per;
  int sum = 0;
  for (int i = 0; i < per; ++i) {
    int idx = base + i;
    if (idx < n) sum += deg[idx];
  }
  part[tid] = sum;
  __syncthreads();
  // Hillis-Steele inclusive scan
  for (int off = 1; off < 1024; off <<= 1) {
    int v = (tid >= off) ? part[tid - off] : 0;
    __syncthreads();
    part[tid] += v;
    __syncthreads();
  }
  int run = (tid == 0) ? 0 : part[tid - 1];
  for (int i = 0; i < per; ++i) {
    int idx = base + i;
    if (idx < n) { offs[idx] = run; run += deg[idx]; }
  }
  if (tid == 0) offs[n] = part[1023];
}

__global__ __launch_bounds__(256) void scatter_kernel(
    const int* __restrict__ esrc, const int* __restrict__ edst,
    const float* __restrict__ ew, const int* __restrict__ offs,
    int* __restrict__ cursor, int* __restrict__ csrc, float* __restrict__ cw,
    int E) {
  int e = blockIdx.x * 256 + threadIdx.x;
  if (e < E) {
    int d = edst[e];
    int p = atomicAdd(&cursor[d], 1);
    int i = offs[d] + p;
    csrc[i] = esrc[e];
    cw[i] = ew[e];
  }
}

// ---------------- GEMM1: support[N,128] = x[N,512] @ W1[512,128] ----------------
__global__ __launch_bounds__(256) void gemm1_kernel(
    const float* __restrict__ x, const float* __restrict__ W1,
    float* __restrict__ support, int nrows) {
  __shared__ float sx[64][33];
  __shared__ float sw[32][132];
  const int tid = threadIdx.x;
  const int tx = tid & 15;
  const int ty = tid >> 4;
  const int row0 = blockIdx.x * 64;

  float acc[4][8];
#pragma unroll
  for (int i = 0; i < 4; ++i)
#pragma unroll
    for (int j = 0; j < 8; ++j) acc[i][j] = 0.f;

  for (int k0 = 0; k0 < NFEAT; k0 += 32) {
#pragma unroll
    for (int i = 0; i < 2; ++i) {
      int f = tid + 256 * i;
      int r = f >> 3, c = (f & 7) << 2;
      float4 v = make_float4(0.f, 0.f, 0.f, 0.f);
      int gr = row0 + r;
      if (gr < nrows) v = *(const float4*)&x[(size_t)gr * NFEAT + k0 + c];
      sx[r][c] = v.x; sx[r][c + 1] = v.y; sx[r][c + 2] = v.z; sx[r][c + 3] = v.w;
    }
#pragma unroll
    for (int i = 0; i < 4; ++i) {
      int f = tid + 256 * i;
      int r = f >> 5, c = (f & 31) << 2;
      float4 v = *(const float4*)&W1[(size_t)(k0 + r) * NHID + c];
      sw[r][c] = v.x; sw[r][c + 1] = v.y; sw[r][c + 2] = v.z; sw[r][c + 3] = v.w;
    }
    __syncthreads();
#pragma unroll
    for (int kk = 0; kk < 32; ++kk) {
      float a[4];
#pragma unroll
      for (int i = 0; i < 4; ++i) a[i] = sx[ty * 4 + i][kk];
      float4 b0 = *(const float4*)&sw[kk][tx * 8];
      float4 b1v = *(const float4*)&sw[kk][tx * 8 + 4];
      float b[8] = {b0.x, b0.y, b0.z, b0.w, b1v.x, b1v.y, b1v.z, b1v.w};
#pragma unroll
      for (int i = 0; i < 4; ++i)
#pragma unroll
        for (int j = 0; j < 8; ++j) acc[i][j] += a[i] * b[j];
    }
    __syncthreads();
  }
#pragma unroll
  for (int i = 0; i < 4; ++i) {
    int gr = row0 + ty * 4 + i;
    if (gr < nrows) {
      float4 v0 = make_float4(acc[i][0], acc[i][1], acc[i][2], acc[i][3]);
      float4 v1 = make_float4(acc[i][4], acc[i][5], acc[i][6], acc[i][7]);
      *(float4*)&support[(size_t)gr * NHID + tx * 8] = v0;
      *(float4*)&support[(size_t)gr * NHID + tx * 8 + 4] = v1;
    }
  }
}

// ------- SpMM1 gather: h[n,f] = relu(b1[f] + sum_e w_e * support[src_e, f]) -------
// 128 threads per node (one feat each), 2 nodes per block.
__global__ __launch_bounds__(256) void spmm1_gather(
    const int* __restrict__ offs, const int* __restrict__ csrc,
    const float* __restrict__ cw, const float* __restrict__ support,
    const float* __restrict__ b1, float* __restrict__ h, int n) {
  int node = blockIdx.x * 2 + (threadIdx.x >> 7);
  int f = threadIdx.x & 127;
  if (node >= n) return;
  int beg = offs[node], end = offs[node + 1];
  float acc = 0.f;
  int i = beg;
  for (; i + 1 < end; i += 2) {
    int s0 = csrc[i], s1 = csrc[i + 1];
    float w0 = cw[i], w1 = cw[i + 1];
    float v0 = support[(size_t)s0 * NHID + f];
    float v1 = support[(size_t)s1 * NHID + f];
    acc += w0 * v0;
    acc += w1 * v1;
  }
  if (i < end) acc += cw[i] * support[(size_t)csrc[i] * NHID + f];
  h[(size_t)node * NHID + f] = fmaxf(acc + b1[f], 0.f);
}

// ------- GEMM2: s2[N,40] = h @ W2[128,40] (h already has bias+relu) ------
__global__ __launch_bounds__(256) void gemm2_kernel(
    const float* __restrict__ h, const float* __restrict__ W2,
    float* __restrict__ s2, int nrows) {
  __shared__ float sh[32][128];
  __shared__ float swt[128][40];
  const int tid = threadIdx.x;
  for (int i = tid; i < 128 * 40; i += 256) swt[i / 40][i % 40] = W2[i];
  __syncthreads();
  const int row0 = blockIdx.x * 32;
#pragma unroll
  for (int i = 0; i < 4; ++i) {
    int f = tid + 256 * i;
    int r = f >> 5, c = (f & 31) << 2;
    int gr = row0 + r;
    float4 v = make_float4(0.f, 0.f, 0.f, 0.f);
    if (gr < nrows) v = *(const float4*)&h[(size_t)gr * NHID + c];
    sh[r][c] = v.x; sh[r][c + 1] = v.y; sh[r][c + 2] = v.z; sh[r][c + 3] = v.w;
  }
  __syncthreads();
#pragma unroll
  for (int j = 0; j < 5; ++j) {
    int o = tid + 256 * j;
    int r = o / 40, c = o % 40;
    float acc = 0.f;
#pragma unroll 8
    for (int k = 0; k < 128; ++k) acc += sh[r][k] * swt[k][c];
    int gr = row0 + r;
    if (gr < nrows) s2[(size_t)gr * NCLS + c] = acc;
  }
}

// ------- SpMM2 gather: out[n,c] = b2[c] + sum_e w_e * s2[src_e, c] -------
// one wave (64 lanes, 40 active) per node, 4 nodes per block.
__global__ __launch_bounds__(256) void spmm2_gather(
    const int* __restrict__ offs, const int* __restrict__ csrc,
    const float* __restrict__ cw, const float* __restrict__ s2,
    const float* __restrict__ b2, float* __restrict__ out, int n) {
  int node = blockIdx.x * 4 + (threadIdx.x >> 6);
  int f = threadIdx.x & 63;
  if (node >= n || f >= NCLS) return;
  int beg = offs[node], end = offs[node + 1];
  float acc = 0.f;
  int i = beg;
  for (; i + 1 < end; i += 2) {
    int s0 = csrc[i], s1 = csrc[i + 1];
    float w0 = cw[i], w1 = cw[i + 1];
    acc += w0 * s2[(size_t)s0 * NCLS + f];
    acc += w1 * s2[(size_t)s1 * NCLS + f];
  }
  if (i < end) acc += cw[i] * s2[(size_t)csrc[i] * NCLS + f];
  out[(size_t)node * NCLS + f] = acc + b2[f];
}

extern "C" void kernel_launch(void* const* d_in, const int* in_sizes, int n_in,
                              void* d_out, int out_size, void* d_ws, size_t ws_size,
                              hipStream_t stream) {
  const float* x   = (const float*)d_in[0];
  const float* W1  = (const float*)d_in[1];
  const float* b1  = (const float*)d_in[2];
  const float* W2  = (const float*)d_in[3];
  const float* b2  = (const float*)d_in[4];
  const int* esrc  = (const int*)d_in[5];
  const int* edst  = (const int*)d_in[6];
  const float* ew  = (const float*)d_in[7];
  float* out = (float*)d_out;

  const int N = in_sizes[0] / NFEAT;   // 50000
  const int E = in_sizes[5];           // 800000

  char* ws = (char*)d_ws;
  size_t off = 0;
  auto alloc = [&](size_t bytes) {
    void* p = ws + off;
    off += (bytes + 255) & ~(size_t)255;
    return p;
  };
  int*   csrc    = (int*)alloc((size_t)E * 4);
  float* cw      = (float*)alloc((size_t)E * 4);
  int*   offs    = (int*)alloc((size_t)(N + 1) * 4);
  int*   degcur  = (int*)alloc((size_t)2 * N * 4);   // deg | cursor, zeroed together
  int*   deg     = degcur;
  int*   cursor  = degcur + N;
  float* support = (float*)alloc((size_t)N * NHID * 4);
  float* h       = (float*)alloc((size_t)N * NHID * 4);
  float* s2      = support;  // support dead after spmm1; alias for s2 (N*40 <= N*128)

  // ---- CSR build (int atomics only) ----
  hipMemsetAsync(degcur, 0, (size_t)2 * N * 4, stream);
  hist_kernel<<<(E + 255) / 256, 256, 0, stream>>>(edst, deg, E);
  scan_kernel<<<1, 1024, 0, stream>>>(deg, offs, N);
  scatter_kernel<<<(E + 255) / 256, 256, 0, stream>>>(esrc, edst, ew, offs, cursor,
                                                      csrc, cw, E);

  // ---- layer 1 ----
  gemm1_kernel<<<(N + 63) / 64, 256, 0, stream>>>(x, W1, support, N);
  spmm1_gather<<<(N + 1) / 2, 256, 0, stream>>>(offs, csrc, cw, support, b1, h, N);

  // ---- layer 2 ----
  gemm2_kernel<<<(N + 31) / 32, 256, 0, stream>>>(h, W2, s2, N);
  spmm2_gather<<<(N + 3) / 4, 256, 0, stream>>>(offs, csrc, cw, s2, b2, out, N);
}

// Round 3
// 356.264 us; speedup vs baseline: 5.6264x; 1.3308x over previous
//
#include <hip/hip_runtime.h>
#include <hip/hip_bf16.h>

// GCN forward: out = spmm(A, relu(spmm(A, x@W1)+b1) @ W2) + b2
// N=50000, F=512, H=128, C=40, E=800000
// Round 3: GEMM1 -> bf16 MFMA (16x16x32), support stored bf16 (halves spmm1
// gather traffic). CSR-gather SpMM unchanged.

#define NFEAT 512
#define NHID  128
#define NCLS  40

typedef __attribute__((ext_vector_type(8))) short bf16x8;
typedef __attribute__((ext_vector_type(4))) short bf16x4;
typedef __attribute__((ext_vector_type(4))) float f32x4;

__device__ inline short f2bf(float f) {
  __hip_bfloat16 b = __float2bfloat16(f);
  return *reinterpret_cast<short*>(&b);
}

// ---------------- CSR build ----------------
__global__ __launch_bounds__(256) void hist_kernel(
    const int* __restrict__ edst, int* __restrict__ deg, int E) {
  int e = blockIdx.x * 256 + threadIdx.x;
  if (e < E) atomicAdd(&deg[edst[e]], 1);
}

__global__ __launch_bounds__(1024) void scan_kernel(
    const int* __restrict__ deg, int* __restrict__ offs, int n) {
  __shared__ int part[1024];
  const int tid = threadIdx.x;
  const int per = (n + 1023) / 1024;
  const int base = tid * per;
  int sum = 0;
  for (int i = 0; i < per; ++i) {
    int idx = base + i;
    if (idx < n) sum += deg[idx];
  }
  part[tid] = sum;
  __syncthreads();
  for (int off = 1; off < 1024; off <<= 1) {
    int v = (tid >= off) ? part[tid - off] : 0;
    __syncthreads();
    part[tid] += v;
    __syncthreads();
  }
  int run = (tid == 0) ? 0 : part[tid - 1];
  for (int i = 0; i < per; ++i) {
    int idx = base + i;
    if (idx < n) { offs[idx] = run; run += deg[idx]; }
  }
  if (tid == 0) offs[n] = part[1023];
}

__global__ __launch_bounds__(256) void scatter_kernel(
    const int* __restrict__ esrc, const int* __restrict__ edst,
    const float* __restrict__ ew, const int* __restrict__ offs,
    int* __restrict__ cursor, int* __restrict__ csrc, float* __restrict__ cw,
    int E) {
  int e = blockIdx.x * 256 + threadIdx.x;
  if (e < E) {
    int d = edst[e];
    int p = atomicAdd(&cursor[d], 1);
    int i = offs[d] + p;
    csrc[i] = esrc[e];
    cw[i] = ew[e];
  }
}

// ---- W1 [512][128] f32 -> W1t [128][512] bf16 (transpose + convert) ----
__global__ __launch_bounds__(256) void w1t_kernel(
    const float* __restrict__ W1, __hip_bfloat16* __restrict__ W1t) {
  __shared__ float t[64][129];          // [k-local][n], pad kills bank conflicts
  const int tid = threadIdx.x;
  const int k0 = blockIdx.x * 64;
#pragma unroll
  for (int i = 0; i < 8; ++i) {
    int f = i * 256 + tid;              // float4 over 64x128
    int r = f >> 5, c = (f & 31) << 2;
    float4 v = *(const float4*)&W1[(size_t)(k0 + r) * NHID + c];
    t[r][c] = v.x; t[r][c + 1] = v.y; t[r][c + 2] = v.z; t[r][c + 3] = v.w;
  }
  __syncthreads();
#pragma unroll
  for (int i = 0; i < 32; ++i) {
    int o = i * 256 + tid;              // 64x128 elements
    int k = o & 63, n = o >> 6;
    W1t[(size_t)n * NFEAT + k0 + k] = __float2bfloat16(t[k][n]);
  }
}

// ---------- GEMM1 (MFMA): support[N,128] = bf16(x) @ bf16(W1), bf16 out ----------
// BM=128, BN=128(full), BK=64. 256 threads = 4 waves in 2x2, 64x64 per wave.
__global__ __launch_bounds__(256) void gemm1_mfma(
    const float* __restrict__ x, const __hip_bfloat16* __restrict__ W1t,
    __hip_bfloat16* __restrict__ support, int nrows) {
  __shared__ __align__(16) char sA[128 * 64 * 2];   // [row 128][k 64] bf16, swizzled
  __shared__ __align__(16) char sB[128 * 64 * 2];   // [n 128][k 64] bf16, swizzled
  const int tid = threadIdx.x;
  const int lane = tid & 63;
  const int wid = tid >> 6;
  const int wm = (wid >> 1) & 1, wn = wid & 1;
  const int row0 = blockIdx.x * 128;
  const int l15 = lane & 15, l4 = lane >> 4;

  f32x4 acc[4][4];
#pragma unroll
  for (int m = 0; m < 4; ++m)
#pragma unroll
    for (int n = 0; n < 4; ++n) acc[m][n] = (f32x4){0.f, 0.f, 0.f, 0.f};

  for (int k0 = 0; k0 < NFEAT; k0 += 64) {
    // stage A: 128x64 f32 -> bf16 (2048 float4, 8/thread)
#pragma unroll
    for (int i = 0; i < 8; ++i) {
      int f = i * 256 + tid;
      int r = f >> 4;                  // 16 float4 per row
      int c = (f & 15) << 2;           // col in floats
      float4 v = make_float4(0.f, 0.f, 0.f, 0.f);
      int gr = row0 + r;
      if (gr < nrows) v = *(const float4*)&x[(size_t)gr * NFEAT + k0 + c];
      bf16x4 s;
      s[0] = f2bf(v.x); s[1] = f2bf(v.y); s[2] = f2bf(v.z); s[3] = f2bf(v.w);
      int byte = (r * 128 + c * 2) ^ ((r & 7) << 4);
      *(bf16x4*)(sA + byte) = s;
    }
    // stage B: W1t rows (n), cols k0..k0+63 (1024 short8, 4/thread)
#pragma unroll
    for (int i = 0; i < 4; ++i) {
      int f = i * 256 + tid;
      int r = f >> 3;                  // 8 short8 per row
      int c = (f & 7) << 3;            // col in bf16
      bf16x8 v = *(const bf16x8*)&W1t[(size_t)r * NFEAT + k0 + c];
      int byte = (r * 128 + c * 2) ^ ((r & 7) << 4);
      *(bf16x8*)(sB + byte) = v;
    }
    __syncthreads();
#pragma unroll
    for (int kk = 0; kk < 64; kk += 32) {
      bf16x8 a[4], b[4];
      int cb = (kk + l4 * 8) * 2;
#pragma unroll
      for (int m = 0; m < 4; ++m) {
        int r = wm * 64 + m * 16 + l15;
        a[m] = *(const bf16x8*)(sA + ((r * 128 + cb) ^ ((r & 7) << 4)));
      }
#pragma unroll
      for (int n = 0; n < 4; ++n) {
        int r = wn * 64 + n * 16 + l15;
        b[n] = *(const bf16x8*)(sB + ((r * 128 + cb) ^ ((r & 7) << 4)));
      }
#pragma unroll
      for (int m = 0; m < 4; ++m)
#pragma unroll
        for (int n = 0; n < 4; ++n)
          acc[m][n] = __builtin_amdgcn_mfma_f32_16x16x32_bf16(a[m], b[n], acc[m][n], 0, 0, 0);
    }
    __syncthreads();
  }
  // C/D layout: col = lane&15, row = (lane>>4)*4 + reg
#pragma unroll
  for (int m = 0; m < 4; ++m) {
#pragma unroll
    for (int r = 0; r < 4; ++r) {
      int grow = row0 + wm * 64 + m * 16 + l4 * 4 + r;
      if (grow < nrows) {
#pragma unroll
        for (int n = 0; n < 4; ++n) {
          int col = wn * 64 + n * 16 + l15;
          support[(size_t)grow * NHID + col] = __float2bfloat16(acc[m][n][r]);
        }
      }
    }
  }
}

// ------- SpMM1 gather: h[n,f] = relu(b1[f] + sum_e w_e * support[src_e, f]) -------
// one wave per node, each lane handles 2 feats (bf16x2 loads).
__global__ __launch_bounds__(256) void spmm1_gather(
    const int* __restrict__ offs, const int* __restrict__ csrc,
    const float* __restrict__ cw, const __hip_bfloat16* __restrict__ support,
    const float* __restrict__ b1, float* __restrict__ h, int n) {
  int node = blockIdx.x * 4 + (threadIdx.x >> 6);
  int f2 = threadIdx.x & 63;
  if (node >= n) return;
  int beg = offs[node], end = offs[node + 1];
  float a0 = 0.f, a1 = 0.f;
  int i = beg;
  for (; i + 1 < end; i += 2) {
    int s0 = csrc[i], s1 = csrc[i + 1];
    float w0 = cw[i], w1 = cw[i + 1];
    unsigned int u0 = *(const unsigned int*)&support[(size_t)s0 * NHID + f2 * 2];
    unsigned int u1 = *(const unsigned int*)&support[(size_t)s1 * NHID + f2 * 2];
    float v00, v01, v10, v11;
    *(unsigned int*)&v00 = (u0 & 0xffffu) << 16;
    *(unsigned int*)&v01 = u0 & 0xffff0000u;
    *(unsigned int*)&v10 = (u1 & 0xffffu) << 16;
    *(unsigned int*)&v11 = u1 & 0xffff0000u;
    a0 += w0 * v00; a1 += w0 * v01;
    a0 += w1 * v10; a1 += w1 * v11;
  }
  if (i < end) {
    float w = cw[i];
    unsigned int u = *(const unsigned int*)&support[(size_t)csrc[i] * NHID + f2 * 2];
    float v0, v1;
    *(unsigned int*)&v0 = (u & 0xffffu) << 16;
    *(unsigned int*)&v1 = u & 0xffff0000u;
    a0 += w * v0; a1 += w * v1;
  }
  float2 o;
  o.x = fmaxf(a0 + b1[f2 * 2], 0.f);
  o.y = fmaxf(a1 + b1[f2 * 2 + 1], 0.f);
  *(float2*)&h[(size_t)node * NHID + f2 * 2] = o;
}

// ------- GEMM2: s2[N,40] = h @ W2[128,40] (h already has bias+relu) ------
__global__ __launch_bounds__(256) void gemm2_kernel(
    const float* __restrict__ h, const float* __restrict__ W2,
    float* __restrict__ s2, int nrows) {
  __shared__ float sh[32][128];
  __shared__ float swt[128][40];
  const int tid = threadIdx.x;
  for (int i = tid; i < 128 * 40; i += 256) swt[i / 40][i % 40] = W2[i];
  __syncthreads();
  const int row0 = blockIdx.x * 32;
#pragma unroll
  for (int i = 0; i < 4; ++i) {
    int f = tid + 256 * i;
    int r = f >> 5, c = (f & 31) << 2;
    int gr = row0 + r;
    float4 v = make_float4(0.f, 0.f, 0.f, 0.f);
    if (gr < nrows) v = *(const float4*)&h[(size_t)gr * NHID + c];
    sh[r][c] = v.x; sh[r][c + 1] = v.y; sh[r][c + 2] = v.z; sh[r][c + 3] = v.w;
  }
  __syncthreads();
#pragma unroll
  for (int j = 0; j < 5; ++j) {
    int o = tid + 256 * j;
    int r = o / 40, c = o % 40;
    float acc = 0.f;
#pragma unroll 8
    for (int k = 0; k < 128; ++k) acc += sh[r][k] * swt[k][c];
    int gr = row0 + r;
    if (gr < nrows) s2[(size_t)gr * NCLS + c] = acc;
  }
}

// ------- SpMM2 gather: out[n,c] = b2[c] + sum_e w_e * s2[src_e, c] -------
__global__ __launch_bounds__(256) void spmm2_gather(
    const int* __restrict__ offs, const int* __restrict__ csrc,
    const float* __restrict__ cw, const float* __restrict__ s2,
    const float* __restrict__ b2, float* __restrict__ out, int n) {
  int node = blockIdx.x * 4 + (threadIdx.x >> 6);
  int f = threadIdx.x & 63;
  if (node >= n || f >= NCLS) return;
  int beg = offs[node], end = offs[node + 1];
  float acc = 0.f;
  int i = beg;
  for (; i + 1 < end; i += 2) {
    int s0 = csrc[i], s1 = csrc[i + 1];
    float w0 = cw[i], w1 = cw[i + 1];
    acc += w0 * s2[(size_t)s0 * NCLS + f];
    acc += w1 * s2[(size_t)s1 * NCLS + f];
  }
  if (i < end) acc += cw[i] * s2[(size_t)csrc[i] * NCLS + f];
  out[(size_t)node * NCLS + f] = acc + b2[f];
}

extern "C" void kernel_launch(void* const* d_in, const int* in_sizes, int n_in,
                              void* d_out, int out_size, void* d_ws, size_t ws_size,
                              hipStream_t stream) {
  const float* x   = (const float*)d_in[0];
  const float* W1  = (const float*)d_in[1];
  const float* b1  = (const float*)d_in[2];
  const float* W2  = (const float*)d_in[3];
  const float* b2  = (const float*)d_in[4];
  const int* esrc  = (const int*)d_in[5];
  const int* edst  = (const int*)d_in[6];
  const float* ew  = (const float*)d_in[7];
  float* out = (float*)d_out;

  const int N = in_sizes[0] / NFEAT;   // 50000
  const int E = in_sizes[5];           // 800000

  char* ws = (char*)d_ws;
  size_t off = 0;
  auto alloc = [&](size_t bytes) {
    void* p = ws + off;
    off += (bytes + 255) & ~(size_t)255;
    return p;
  };
  int*   csrc    = (int*)alloc((size_t)E * 4);
  float* cw      = (float*)alloc((size_t)E * 4);
  int*   offs    = (int*)alloc((size_t)(N + 1) * 4);
  int*   degcur  = (int*)alloc((size_t)2 * N * 4);
  int*   deg     = degcur;
  int*   cursor  = degcur + N;
  __hip_bfloat16* W1t     = (__hip_bfloat16*)alloc((size_t)NHID * NFEAT * 2);
  __hip_bfloat16* support = (__hip_bfloat16*)alloc((size_t)N * NHID * 2);
  float* h       = (float*)alloc((size_t)N * NHID * 4);
  float* s2      = (float*)alloc((size_t)N * NCLS * 4);

  // ---- CSR build (int atomics only) ----
  hipMemsetAsync(degcur, 0, (size_t)2 * N * 4, stream);
  hist_kernel<<<(E + 255) / 256, 256, 0, stream>>>(edst, deg, E);
  scan_kernel<<<1, 1024, 0, stream>>>(deg, offs, N);
  scatter_kernel<<<(E + 255) / 256, 256, 0, stream>>>(esrc, edst, ew, offs, cursor,
                                                      csrc, cw, E);

  // ---- layer 1 ----
  w1t_kernel<<<NFEAT / 64, 256, 0, stream>>>(W1, W1t);
  gemm1_mfma<<<(N + 127) / 128, 256, 0, stream>>>(x, W1t, support, N);
  spmm1_gather<<<(N + 3) / 4, 256, 0, stream>>>(offs, csrc, cw, support, b1, h, N);

  // ---- layer 2 ----
  gemm2_kernel<<<(N + 31) / 32, 256, 0, stream>>>(h, W2, s2, N);
  spmm2_gather<<<(N + 3) / 4, 256, 0, stream>>>(offs, csrc, cw, s2, b2, out, N);
}

// Round 4
// 276.853 us; speedup vs baseline: 7.2402x; 1.2868x over previous
//
#include <hip/hip_runtime.h>
#include <hip/hip_bf16.h>

// GCN forward: out = spmm(A, relu(spmm(A, x@W1)+b1) @ W2) + b2
// N=50000, F=512, H=128, C=40, E=800000
// Round 4: replace 94us single-block scan with 3-phase parallel block scan.

#define NFEAT 512
#define NHID  128
#define NCLS  40

typedef __attribute__((ext_vector_type(8))) short bf16x8;
typedef __attribute__((ext_vector_type(4))) short bf16x4;
typedef __attribute__((ext_vector_type(4))) float f32x4;

__device__ inline short f2bf(float f) {
  __hip_bfloat16 b = __float2bfloat16(f);
  return *reinterpret_cast<short*>(&b);
}

// ---------------- CSR build ----------------
__global__ __launch_bounds__(256) void hist_kernel(
    const int* __restrict__ edst, int* __restrict__ deg, int E) {
  int e = blockIdx.x * 256 + threadIdx.x;
  if (e < E) atomicAdd(&deg[edst[e]], 1);
}

// phase 1: per-256-chunk sums
__global__ __launch_bounds__(256) void scan_part(
    const int* __restrict__ deg, int* __restrict__ bsum, int n) {
  __shared__ int ws[4];
  int idx = blockIdx.x * 256 + threadIdx.x;
  int v = (idx < n) ? deg[idx] : 0;
#pragma unroll
  for (int o = 32; o > 0; o >>= 1) v += __shfl_down(v, o, 64);
  int lane = threadIdx.x & 63, w = threadIdx.x >> 6;
  if (lane == 0) ws[w] = v;
  __syncthreads();
  if (threadIdx.x == 0) bsum[blockIdx.x] = ws[0] + ws[1] + ws[2] + ws[3];
}

// phase 2: single small block scans the <=1024 chunk sums -> exclusive boff,
// writes offs[n] = total.
__global__ __launch_bounds__(1024) void scan_top(
    const int* __restrict__ bsum, int* __restrict__ boff,
    int* __restrict__ offs, int nchunk, int n) {
  __shared__ int part[1024];
  int tid = threadIdx.x;
  int v = (tid < nchunk) ? bsum[tid] : 0;
  part[tid] = v;
  __syncthreads();
  for (int o = 1; o < 1024; o <<= 1) {
    int t = (tid >= o) ? part[tid - o] : 0;
    __syncthreads();
    part[tid] += t;
    __syncthreads();
  }
  if (tid < nchunk) boff[tid] = part[tid] - v;   // exclusive
  if (tid == 0) offs[n] = part[nchunk - 1];
}

// phase 3: per-chunk exclusive scan + chunk offset
__global__ __launch_bounds__(256) void scan_apply(
    const int* __restrict__ deg, const int* __restrict__ boff,
    int* __restrict__ offs, int n) {
  __shared__ int part[256];
  int tid = threadIdx.x;
  int idx = blockIdx.x * 256 + tid;
  int v = (idx < n) ? deg[idx] : 0;
  part[tid] = v;
  __syncthreads();
  for (int o = 1; o < 256; o <<= 1) {
    int t = (tid >= o) ? part[tid - o] : 0;
    __syncthreads();
    part[tid] += t;
    __syncthreads();
  }
  if (idx < n) offs[idx] = boff[blockIdx.x] + part[tid] - v;
}

__global__ __launch_bounds__(256) void scatter_kernel(
    const int* __restrict__ esrc, const int* __restrict__ edst,
    const float* __restrict__ ew, const int* __restrict__ offs,
    int* __restrict__ cursor, int* __restrict__ csrc, float* __restrict__ cw,
    int E) {
  int e = blockIdx.x * 256 + threadIdx.x;
  if (e < E) {
    int d = edst[e];
    int p = atomicAdd(&cursor[d], 1);
    int i = offs[d] + p;
    csrc[i] = esrc[e];
    cw[i] = ew[e];
  }
}

// ---- W1 [512][128] f32 -> W1t [128][512] bf16 (transpose + convert) ----
__global__ __launch_bounds__(256) void w1t_kernel(
    const float* __restrict__ W1, __hip_bfloat16* __restrict__ W1t) {
  __shared__ float t[64][129];
  const int tid = threadIdx.x;
  const int k0 = blockIdx.x * 64;
#pragma unroll
  for (int i = 0; i < 8; ++i) {
    int f = i * 256 + tid;
    int r = f >> 5, c = (f & 31) << 2;
    float4 v = *(const float4*)&W1[(size_t)(k0 + r) * NHID + c];
    t[r][c] = v.x; t[r][c + 1] = v.y; t[r][c + 2] = v.z; t[r][c + 3] = v.w;
  }
  __syncthreads();
#pragma unroll
  for (int i = 0; i < 32; ++i) {
    int o = i * 256 + tid;
    int k = o & 63, n = o >> 6;
    W1t[(size_t)n * NFEAT + k0 + k] = __float2bfloat16(t[k][n]);
  }
}

// ---------- GEMM1 (MFMA): support[N,128] = bf16(x) @ bf16(W1), bf16 out ----------
__global__ __launch_bounds__(256) void gemm1_mfma(
    const float* __restrict__ x, const __hip_bfloat16* __restrict__ W1t,
    __hip_bfloat16* __restrict__ support, int nrows) {
  __shared__ __align__(16) char sA[128 * 64 * 2];
  __shared__ __align__(16) char sB[128 * 64 * 2];
  const int tid = threadIdx.x;
  const int lane = tid & 63;
  const int wid = tid >> 6;
  const int wm = (wid >> 1) & 1, wn = wid & 1;
  const int row0 = blockIdx.x * 128;
  const int l15 = lane & 15, l4 = lane >> 4;

  f32x4 acc[4][4];
#pragma unroll
  for (int m = 0; m < 4; ++m)
#pragma unroll
    for (int n = 0; n < 4; ++n) acc[m][n] = (f32x4){0.f, 0.f, 0.f, 0.f};

  for (int k0 = 0; k0 < NFEAT; k0 += 64) {
#pragma unroll
    for (int i = 0; i < 8; ++i) {
      int f = i * 256 + tid;
      int r = f >> 4;
      int c = (f & 15) << 2;
      float4 v = make_float4(0.f, 0.f, 0.f, 0.f);
      int gr = row0 + r;
      if (gr < nrows) v = *(const float4*)&x[(size_t)gr * NFEAT + k0 + c];
      bf16x4 s;
      s[0] = f2bf(v.x); s[1] = f2bf(v.y); s[2] = f2bf(v.z); s[3] = f2bf(v.w);
      int byte = (r * 128 + c * 2) ^ ((r & 7) << 4);
      *(bf16x4*)(sA + byte) = s;
    }
#pragma unroll
    for (int i = 0; i < 4; ++i) {
      int f = i * 256 + tid;
      int r = f >> 3;
      int c = (f & 7) << 3;
      bf16x8 v = *(const bf16x8*)&W1t[(size_t)r * NFEAT + k0 + c];
      int byte = (r * 128 + c * 2) ^ ((r & 7) << 4);
      *(bf16x8*)(sB + byte) = v;
    }
    __syncthreads();
#pragma unroll
    for (int kk = 0; kk < 64; kk += 32) {
      bf16x8 a[4], b[4];
      int cb = (kk + l4 * 8) * 2;
#pragma unroll
      for (int m = 0; m < 4; ++m) {
        int r = wm * 64 + m * 16 + l15;
        a[m] = *(const bf16x8*)(sA + ((r * 128 + cb) ^ ((r & 7) << 4)));
      }
#pragma unroll
      for (int n = 0; n < 4; ++n) {
        int r = wn * 64 + n * 16 + l15;
        b[n] = *(const bf16x8*)(sB + ((r * 128 + cb) ^ ((r & 7) << 4)));
      }
#pragma unroll
      for (int m = 0; m < 4; ++m)
#pragma unroll
        for (int n = 0; n < 4; ++n)
          acc[m][n] = __builtin_amdgcn_mfma_f32_16x16x32_bf16(a[m], b[n], acc[m][n], 0, 0, 0);
    }
    __syncthreads();
  }
#pragma unroll
  for (int m = 0; m < 4; ++m) {
#pragma unroll
    for (int r = 0; r < 4; ++r) {
      int grow = row0 + wm * 64 + m * 16 + l4 * 4 + r;
      if (grow < nrows) {
#pragma unroll
        for (int n = 0; n < 4; ++n) {
          int col = wn * 64 + n * 16 + l15;
          support[(size_t)grow * NHID + col] = __float2bfloat16(acc[m][n][r]);
        }
      }
    }
  }
}

// ------- SpMM1 gather: h[n,f] = relu(b1[f] + sum_e w_e * support[src_e, f]) -------
__global__ __launch_bounds__(256) void spmm1_gather(
    const int* __restrict__ offs, const int* __restrict__ csrc,
    const float* __restrict__ cw, const __hip_bfloat16* __restrict__ support,
    const float* __restrict__ b1, float* __restrict__ h, int n) {
  int node = blockIdx.x * 4 + (threadIdx.x >> 6);
  int f2 = threadIdx.x & 63;
  if (node >= n) return;
  int beg = offs[node], end = offs[node + 1];
  float a0 = 0.f, a1 = 0.f;
  int i = beg;
  for (; i + 1 < end; i += 2) {
    int s0 = csrc[i], s1 = csrc[i + 1];
    float w0 = cw[i], w1 = cw[i + 1];
    unsigned int u0 = *(const unsigned int*)&support[(size_t)s0 * NHID + f2 * 2];
    unsigned int u1 = *(const unsigned int*)&support[(size_t)s1 * NHID + f2 * 2];
    float v00, v01, v10, v11;
    *(unsigned int*)&v00 = (u0 & 0xffffu) << 16;
    *(unsigned int*)&v01 = u0 & 0xffff0000u;
    *(unsigned int*)&v10 = (u1 & 0xffffu) << 16;
    *(unsigned int*)&v11 = u1 & 0xffff0000u;
    a0 += w0 * v00; a1 += w0 * v01;
    a0 += w1 * v10; a1 += w1 * v11;
  }
  if (i < end) {
    float w = cw[i];
    unsigned int u = *(const unsigned int*)&support[(size_t)csrc[i] * NHID + f2 * 2];
    float v0, v1;
    *(unsigned int*)&v0 = (u & 0xffffu) << 16;
    *(unsigned int*)&v1 = u & 0xffff0000u;
    a0 += w * v0; a1 += w * v1;
  }
  float2 o;
  o.x = fmaxf(a0 + b1[f2 * 2], 0.f);
  o.y = fmaxf(a1 + b1[f2 * 2 + 1], 0.f);
  *(float2*)&h[(size_t)node * NHID + f2 * 2] = o;
}

// ------- GEMM2: s2[N,40] = h @ W2[128,40] (h already has bias+relu) ------
__global__ __launch_bounds__(256) void gemm2_kernel(
    const float* __restrict__ h, const float* __restrict__ W2,
    float* __restrict__ s2, int nrows) {
  __shared__ float sh[32][128];
  __shared__ float swt[128][40];
  const int tid = threadIdx.x;
  for (int i = tid; i < 128 * 40; i += 256) swt[i / 40][i % 40] = W2[i];
  __syncthreads();
  const int row0 = blockIdx.x * 32;
#pragma unroll
  for (int i = 0; i < 4; ++i) {
    int f = tid + 256 * i;
    int r = f >> 5, c = (f & 31) << 2;
    int gr = row0 + r;
    float4 v = make_float4(0.f, 0.f, 0.f, 0.f);
    if (gr < nrows) v = *(const float4*)&h[(size_t)gr * NHID + c];
    sh[r][c] = v.x; sh[r][c + 1] = v.y; sh[r][c + 2] = v.z; sh[r][c + 3] = v.w;
  }
  __syncthreads();
#pragma unroll
  for (int j = 0; j < 5; ++j) {
    int o = tid + 256 * j;
    int r = o / 40, c = o % 40;
    float acc = 0.f;
#pragma unroll 8
    for (int k = 0; k < 128; ++k) acc += sh[r][k] * swt[k][c];
    int gr = row0 + r;
    if (gr < nrows) s2[(size_t)gr * NCLS + c] = acc;
  }
}

// ------- SpMM2 gather: out[n,c] = b2[c] + sum_e w_e * s2[src_e, c] -------
__global__ __launch_bounds__(256) void spmm2_gather(
    const int* __restrict__ offs, const int* __restrict__ csrc,
    const float* __restrict__ cw, const float* __restrict__ s2,
    const float* __restrict__ b2, float* __restrict__ out, int n) {
  int node = blockIdx.x * 4 + (threadIdx.x >> 6);
  int f = threadIdx.x & 63;
  if (node >= n || f >= NCLS) return;
  int beg = offs[node], end = offs[node + 1];
  float acc = 0.f;
  int i = beg;
  for (; i + 1 < end; i += 2) {
    int s0 = csrc[i], s1 = csrc[i + 1];
    float w0 = cw[i], w1 = cw[i + 1];
    acc += w0 * s2[(size_t)s0 * NCLS + f];
    acc += w1 * s2[(size_t)s1 * NCLS + f];
  }
  if (i < end) acc += cw[i] * s2[(size_t)csrc[i] * NCLS + f];
  out[(size_t)node * NCLS + f] = acc + b2[f];
}

extern "C" void kernel_launch(void* const* d_in, const int* in_sizes, int n_in,
                              void* d_out, int out_size, void* d_ws, size_t ws_size,
                              hipStream_t stream) {
  const float* x   = (const float*)d_in[0];
  const float* W1  = (const float*)d_in[1];
  const float* b1  = (const float*)d_in[2];
  const float* W2  = (const float*)d_in[3];
  const float* b2  = (const float*)d_in[4];
  const int* esrc  = (const int*)d_in[5];
  const int* edst  = (const int*)d_in[6];
  const float* ew  = (const float*)d_in[7];
  float* out = (float*)d_out;

  const int N = in_sizes[0] / NFEAT;   // 50000
  const int E = in_sizes[5];           // 800000
  const int NCHUNK = (N + 255) / 256;  // 196

  char* ws = (char*)d_ws;
  size_t off = 0;
  auto alloc = [&](size_t bytes) {
    void* p = ws + off;
    off += (bytes + 255) & ~(size_t)255;
    return p;
  };
  int*   csrc    = (int*)alloc((size_t)E * 4);
  float* cw      = (float*)alloc((size_t)E * 4);
  int*   offs    = (int*)alloc((size_t)(N + 1) * 4);
  int*   degcur  = (int*)alloc((size_t)2 * N * 4);
  int*   deg     = degcur;
  int*   cursor  = degcur + N;
  int*   bsum    = (int*)alloc((size_t)NCHUNK * 4);
  int*   boff    = (int*)alloc((size_t)NCHUNK * 4);
  __hip_bfloat16* W1t     = (__hip_bfloat16*)alloc((size_t)NHID * NFEAT * 2);
  __hip_bfloat16* support = (__hip_bfloat16*)alloc((size_t)N * NHID * 2);
  float* h       = (float*)alloc((size_t)N * NHID * 4);
  float* s2      = (float*)alloc((size_t)N * NCLS * 4);

  // ---- CSR build (int atomics only) ----
  hipMemsetAsync(degcur, 0, (size_t)2 * N * 4, stream);
  hist_kernel<<<(E + 255) / 256, 256, 0, stream>>>(edst, deg, E);
  scan_part<<<NCHUNK, 256, 0, stream>>>(deg, bsum, N);
  scan_top<<<1, 1024, 0, stream>>>(bsum, boff, offs, NCHUNK, N);
  scan_apply<<<NCHUNK, 256, 0, stream>>>(deg, boff, offs, N);
  scatter_kernel<<<(E + 255) / 256, 256, 0, stream>>>(esrc, edst, ew, offs, cursor,
                                                      csrc, cw, E);

  // ---- layer 1 ----
  w1t_kernel<<<NFEAT / 64, 256, 0, stream>>>(W1, W1t);
  gemm1_mfma<<<(N + 127) / 128, 256, 0, stream>>>(x, W1t, support, N);
  spmm1_gather<<<(N + 3) / 4, 256, 0, stream>>>(offs, csrc, cw, support, b1, h, N);

  // ---- layer 2 ----
  gemm2_kernel<<<(N + 31) / 32, 256, 0, stream>>>(h, W2, s2, N);
  spmm2_gather<<<(N + 3) / 4, 256, 0, stream>>>(offs, csrc, cw, s2, b2, out, N);
}

// Round 5
// 253.966 us; speedup vs baseline: 7.8927x; 1.0901x over previous
//
#include <hip/hip_runtime.h>
#include <hip/hip_bf16.h>

// GCN forward: out = spmm(A, relu(spmm(A, x@W1)+b1) @ W2) + b2
// N=50000, F=512, H=128, C=40, E=800000
// Round 5: gemm1 BM=64 + double-buffer + reg-staged async split (occupancy fix);
// spmm1 unroll4; s2 stored bf16 (halves spmm2 gather traffic).

#define NFEAT 512
#define NHID  128
#define NCLS  40

typedef __attribute__((ext_vector_type(8))) short bf16x8;
typedef __attribute__((ext_vector_type(4))) short bf16x4;
typedef __attribute__((ext_vector_type(4))) float f32x4;

__device__ inline short f2bf(float f) {
  __hip_bfloat16 b = __float2bfloat16(f);
  return *reinterpret_cast<short*>(&b);
}

// ---------------- CSR build ----------------
__global__ __launch_bounds__(256) void hist_kernel(
    const int* __restrict__ edst, int* __restrict__ deg, int E) {
  int e = blockIdx.x * 256 + threadIdx.x;
  if (e < E) atomicAdd(&deg[edst[e]], 1);
}

__global__ __launch_bounds__(256) void scan_part(
    const int* __restrict__ deg, int* __restrict__ bsum, int n) {
  __shared__ int ws[4];
  int idx = blockIdx.x * 256 + threadIdx.x;
  int v = (idx < n) ? deg[idx] : 0;
#pragma unroll
  for (int o = 32; o > 0; o >>= 1) v += __shfl_down(v, o, 64);
  int lane = threadIdx.x & 63, w = threadIdx.x >> 6;
  if (lane == 0) ws[w] = v;
  __syncthreads();
  if (threadIdx.x == 0) bsum[blockIdx.x] = ws[0] + ws[1] + ws[2] + ws[3];
}

__global__ __launch_bounds__(1024) void scan_top(
    const int* __restrict__ bsum, int* __restrict__ boff,
    int* __restrict__ offs, int nchunk, int n) {
  __shared__ int part[1024];
  int tid = threadIdx.x;
  int v = (tid < nchunk) ? bsum[tid] : 0;
  part[tid] = v;
  __syncthreads();
  for (int o = 1; o < 1024; o <<= 1) {
    int t = (tid >= o) ? part[tid - o] : 0;
    __syncthreads();
    part[tid] += t;
    __syncthreads();
  }
  if (tid < nchunk) boff[tid] = part[tid] - v;
  if (tid == 0) offs[n] = part[nchunk - 1];
}

__global__ __launch_bounds__(256) void scan_apply(
    const int* __restrict__ deg, const int* __restrict__ boff,
    int* __restrict__ offs, int n) {
  __shared__ int part[256];
  int tid = threadIdx.x;
  int idx = blockIdx.x * 256 + tid;
  int v = (idx < n) ? deg[idx] : 0;
  part[tid] = v;
  __syncthreads();
  for (int o = 1; o < 256; o <<= 1) {
    int t = (tid >= o) ? part[tid - o] : 0;
    __syncthreads();
    part[tid] += t;
    __syncthreads();
  }
  if (idx < n) offs[idx] = boff[blockIdx.x] + part[tid] - v;
}

__global__ __launch_bounds__(256) void scatter_kernel(
    const int* __restrict__ esrc, const int* __restrict__ edst,
    const float* __restrict__ ew, const int* __restrict__ offs,
    int* __restrict__ cursor, int* __restrict__ csrc, float* __restrict__ cw,
    int E) {
  int e = blockIdx.x * 256 + threadIdx.x;
  if (e < E) {
    int d = edst[e];
    int p = atomicAdd(&cursor[d], 1);
    int i = offs[d] + p;
    csrc[i] = esrc[e];
    cw[i] = ew[e];
  }
}

// ---- W1 [512][128] f32 -> W1t [128][512] bf16 (transpose + convert) ----
__global__ __launch_bounds__(256) void w1t_kernel(
    const float* __restrict__ W1, __hip_bfloat16* __restrict__ W1t) {
  __shared__ float t[64][129];
  const int tid = threadIdx.x;
  const int k0 = blockIdx.x * 64;
#pragma unroll
  for (int i = 0; i < 8; ++i) {
    int f = i * 256 + tid;
    int r = f >> 5, c = (f & 31) << 2;
    float4 v = *(const float4*)&W1[(size_t)(k0 + r) * NHID + c];
    t[r][c] = v.x; t[r][c + 1] = v.y; t[r][c + 2] = v.z; t[r][c + 3] = v.w;
  }
  __syncthreads();
#pragma unroll
  for (int i = 0; i < 32; ++i) {
    int o = i * 256 + tid;
    int k = o & 63, n = o >> 6;
    W1t[(size_t)n * NFEAT + k0 + k] = __float2bfloat16(t[k][n]);
  }
}

// ---------- GEMM1 (MFMA): support[N,128] = bf16(x) @ bf16(W1), bf16 out ----------
// BM=64, BN=128, BK=64. 256 threads = 4 waves (2x2), 32x64 per wave.
// Double-buffered LDS, reg-staged loads issued before MFMA (T14 split).
__global__ __launch_bounds__(256) void gemm1_mfma(
    const float* __restrict__ x, const __hip_bfloat16* __restrict__ W1t,
    __hip_bfloat16* __restrict__ support, int nrows) {
  __shared__ __align__(16) char sA[2][64 * 64 * 2];    // 8 KB each
  __shared__ __align__(16) char sB[2][128 * 64 * 2];   // 16 KB each
  const int tid = threadIdx.x;
  const int lane = tid & 63;
  const int wid = tid >> 6;
  const int wm = wid >> 1, wn = wid & 1;
  const int row0 = blockIdx.x * 64;
  const int l15 = lane & 15, l4 = lane >> 4;

  // per-thread staging coords
  const int ar = tid >> 2;                 // A: row (16 float4/row -> 4 thr/row... )
  // A tile 64x64 f32 = 1024 float4, 4/thread: f = i*256+tid, r=f>>4, c=(f&15)<<2
  // B tile 128x64 bf16 = 1024 bf16x8, 4/thread: r=f>>3, c=(f&7)<<3
  (void)ar;

  f32x4 acc[2][4];
#pragma unroll
  for (int m = 0; m < 2; ++m)
#pragma unroll
    for (int n = 0; n < 4; ++n) acc[m][n] = (f32x4){0.f, 0.f, 0.f, 0.f};

  float4 ra[4];
  bf16x8 rb[4];

  auto LOADT = [&](int k0) {
#pragma unroll
    for (int i = 0; i < 4; ++i) {
      int f = i * 256 + tid;
      int r = f >> 4, c = (f & 15) << 2;
      int gr = row0 + r;
      float4 v = make_float4(0.f, 0.f, 0.f, 0.f);
      if (gr < nrows) v = *(const float4*)&x[(size_t)gr * NFEAT + k0 + c];
      ra[i] = v;
    }
#pragma unroll
    for (int i = 0; i < 4; ++i) {
      int f = i * 256 + tid;
      int r = f >> 3, c = (f & 7) << 3;
      rb[i] = *(const bf16x8*)&W1t[(size_t)r * NFEAT + k0 + c];
    }
  };
  auto WRITET = [&](int buf) {
#pragma unroll
    for (int i = 0; i < 4; ++i) {
      int f = i * 256 + tid;
      int r = f >> 4, c = (f & 15) << 2;
      bf16x4 s;
      s[0] = f2bf(ra[i].x); s[1] = f2bf(ra[i].y);
      s[2] = f2bf(ra[i].z); s[3] = f2bf(ra[i].w);
      int byte = (r * 128 + c * 2) ^ ((r & 7) << 4);
      *(bf16x4*)(sA[buf] + byte) = s;
    }
#pragma unroll
    for (int i = 0; i < 4; ++i) {
      int f = i * 256 + tid;
      int r = f >> 3, c = (f & 7) << 3;
      int byte = (r * 128 + c * 2) ^ ((r & 7) << 4);
      *(bf16x8*)(sB[buf] + byte) = rb[i];
    }
  };
  auto COMP = [&](int buf) {
#pragma unroll
    for (int kk = 0; kk < 64; kk += 32) {
      bf16x8 a[2], b[4];
      int cb = (kk + l4 * 8) * 2;
#pragma unroll
      for (int m = 0; m < 2; ++m) {
        int r = wm * 32 + m * 16 + l15;
        a[m] = *(const bf16x8*)(sA[buf] + ((r * 128 + cb) ^ ((r & 7) << 4)));
      }
#pragma unroll
      for (int n = 0; n < 4; ++n) {
        int r = wn * 64 + n * 16 + l15;
        b[n] = *(const bf16x8*)(sB[buf] + ((r * 128 + cb) ^ ((r & 7) << 4)));
      }
#pragma unroll
      for (int m = 0; m < 2; ++m)
#pragma unroll
        for (int n = 0; n < 4; ++n)
          acc[m][n] = __builtin_amdgcn_mfma_f32_16x16x32_bf16(a[m], b[n], acc[m][n], 0, 0, 0);
    }
  };

  LOADT(0);
  WRITET(0);
  __syncthreads();
  for (int t = 0; t < 8; ++t) {
    int cur = t & 1;
    if (t < 7) LOADT((t + 1) * 64);   // issue next-tile loads (latency hides under MFMA)
    COMP(cur);
    if (t < 7) WRITET(cur ^ 1);
    __syncthreads();
  }

  // C/D layout: col = lane&15, row = (lane>>4)*4 + reg
#pragma unroll
  for (int m = 0; m < 2; ++m) {
#pragma unroll
    for (int r = 0; r < 4; ++r) {
      int grow = row0 + wm * 32 + m * 16 + l4 * 4 + r;
      if (grow < nrows) {
#pragma unroll
        for (int n = 0; n < 4; ++n) {
          int col = wn * 64 + n * 16 + l15;
          support[(size_t)grow * NHID + col] = __float2bfloat16(acc[m][n][r]);
        }
      }
    }
  }
}

// ------- SpMM1 gather: h[n,f] = relu(b1[f] + sum_e w_e * support[src_e, f]) -------
// one wave per node, 2 feats/lane, unroll 4 (4 gathers in flight).
__device__ inline void bf2unpack(unsigned int u, float& lo, float& hi) {
  union { unsigned int ui; float f; } a, b;
  a.ui = (u & 0xffffu) << 16;
  b.ui = u & 0xffff0000u;
  lo = a.f; hi = b.f;
}

__global__ __launch_bounds__(256) void spmm1_gather(
    const int* __restrict__ offs, const int* __restrict__ csrc,
    const float* __restrict__ cw, const __hip_bfloat16* __restrict__ support,
    const float* __restrict__ b1, float* __restrict__ h, int n) {
  int node = blockIdx.x * 4 + (threadIdx.x >> 6);
  int f2 = threadIdx.x & 63;
  if (node >= n) return;
  int beg = offs[node], end = offs[node + 1];
  float a0 = 0.f, a1 = 0.f;
  const unsigned int* sp = (const unsigned int*)support;
  int i = beg;
  for (; i + 3 < end; i += 4) {
    int s0 = csrc[i], s1 = csrc[i + 1], s2i = csrc[i + 2], s3 = csrc[i + 3];
    float w0 = cw[i], w1 = cw[i + 1], w2 = cw[i + 2], w3 = cw[i + 3];
    unsigned int u0 = sp[(size_t)s0 * 64 + f2];
    unsigned int u1 = sp[(size_t)s1 * 64 + f2];
    unsigned int u2 = sp[(size_t)s2i * 64 + f2];
    unsigned int u3 = sp[(size_t)s3 * 64 + f2];
    float lo, hi;
    bf2unpack(u0, lo, hi); a0 += w0 * lo; a1 += w0 * hi;
    bf2unpack(u1, lo, hi); a0 += w1 * lo; a1 += w1 * hi;
    bf2unpack(u2, lo, hi); a0 += w2 * lo; a1 += w2 * hi;
    bf2unpack(u3, lo, hi); a0 += w3 * lo; a1 += w3 * hi;
  }
  for (; i < end; ++i) {
    float w = cw[i];
    unsigned int u = sp[(size_t)csrc[i] * 64 + f2];
    float lo, hi;
    bf2unpack(u, lo, hi);
    a0 += w * lo; a1 += w * hi;
  }
  float2 o;
  o.x = fmaxf(a0 + b1[f2 * 2], 0.f);
  o.y = fmaxf(a1 + b1[f2 * 2 + 1], 0.f);
  *(float2*)&h[(size_t)node * NHID + f2 * 2] = o;
}

// ------- GEMM2: s2[N,40] = h @ W2[128,40] -> bf16 out ------
__global__ __launch_bounds__(256) void gemm2_kernel(
    const float* __restrict__ h, const float* __restrict__ W2,
    __hip_bfloat16* __restrict__ s2, int nrows) {
  __shared__ float sh[32][128];
  __shared__ float swt[128][40];
  const int tid = threadIdx.x;
  for (int i = tid; i < 128 * 40; i += 256) swt[i / 40][i % 40] = W2[i];
  __syncthreads();
  const int row0 = blockIdx.x * 32;
#pragma unroll
  for (int i = 0; i < 4; ++i) {
    int f = tid + 256 * i;
    int r = f >> 5, c = (f & 31) << 2;
    int gr = row0 + r;
    float4 v = make_float4(0.f, 0.f, 0.f, 0.f);
    if (gr < nrows) v = *(const float4*)&h[(size_t)gr * NHID + c];
    sh[r][c] = v.x; sh[r][c + 1] = v.y; sh[r][c + 2] = v.z; sh[r][c + 3] = v.w;
  }
  __syncthreads();
#pragma unroll
  for (int j = 0; j < 5; ++j) {
    int o = tid + 256 * j;
    int r = o / 40, c = o % 40;
    float acc = 0.f;
#pragma unroll 8
    for (int k = 0; k < 128; ++k) acc += sh[r][k] * swt[k][c];
    int gr = row0 + r;
    if (gr < nrows) s2[(size_t)gr * NCLS + c] = __float2bfloat16(acc);
  }
}

// ------- SpMM2 gather: out[n,c] = b2[c] + sum_e w_e * s2[src_e, c] -------
// 32-lane group per node (20 active lanes, 2 feats each), unroll 4.
__global__ __launch_bounds__(256) void spmm2_gather(
    const int* __restrict__ offs, const int* __restrict__ csrc,
    const float* __restrict__ cw, const __hip_bfloat16* __restrict__ s2,
    const float* __restrict__ b2, float* __restrict__ out, int n) {
  int node = blockIdx.x * 8 + (threadIdx.x >> 5);
  int f2 = threadIdx.x & 31;
  if (node >= n || f2 >= 20) return;
  int beg = offs[node], end = offs[node + 1];
  float a0 = 0.f, a1 = 0.f;
  const unsigned int* sp = (const unsigned int*)s2;
  int i = beg;
  for (; i + 3 < end; i += 4) {
    int s0 = csrc[i], s1 = csrc[i + 1], s2i = csrc[i + 2], s3 = csrc[i + 3];
    float w0 = cw[i], w1 = cw[i + 1], w2 = cw[i + 2], w3 = cw[i + 3];
    unsigned int u0 = sp[(size_t)s0 * 20 + f2];
    unsigned int u1 = sp[(size_t)s1 * 20 + f2];
    unsigned int u2 = sp[(size_t)s2i * 20 + f2];
    unsigned int u3 = sp[(size_t)s3 * 20 + f2];
    float lo, hi;
    bf2unpack(u0, lo, hi); a0 += w0 * lo; a1 += w0 * hi;
    bf2unpack(u1, lo, hi); a0 += w1 * lo; a1 += w1 * hi;
    bf2unpack(u2, lo, hi); a0 += w2 * lo; a1 += w2 * hi;
    bf2unpack(u3, lo, hi); a0 += w3 * lo; a1 += w3 * hi;
  }
  for (; i < end; ++i) {
    float w = cw[i];
    unsigned int u = sp[(size_t)csrc[i] * 20 + f2];
    float lo, hi;
    bf2unpack(u, lo, hi);
    a0 += w * lo; a1 += w * hi;
  }
  float2 o;
  o.x = a0 + b2[f2 * 2];
  o.y = a1 + b2[f2 * 2 + 1];
  *(float2*)&out[(size_t)node * NCLS + f2 * 2] = o;
}

extern "C" void kernel_launch(void* const* d_in, const int* in_sizes, int n_in,
                              void* d_out, int out_size, void* d_ws, size_t ws_size,
                              hipStream_t stream) {
  const float* x   = (const float*)d_in[0];
  const float* W1  = (const float*)d_in[1];
  const float* b1  = (const float*)d_in[2];
  const float* W2  = (const float*)d_in[3];
  const float* b2  = (const float*)d_in[4];
  const int* esrc  = (const int*)d_in[5];
  const int* edst  = (const int*)d_in[6];
  const float* ew  = (const float*)d_in[7];
  float* out = (float*)d_out;

  const int N = in_sizes[0] / NFEAT;   // 50000
  const int E = in_sizes[5];           // 800000
  const int NCHUNK = (N + 255) / 256;  // 196

  char* ws = (char*)d_ws;
  size_t off = 0;
  auto alloc = [&](size_t bytes) {
    void* p = ws + off;
    off += (bytes + 255) & ~(size_t)255;
    return p;
  };
  int*   csrc    = (int*)alloc((size_t)E * 4);
  float* cw      = (float*)alloc((size_t)E * 4);
  int*   offs    = (int*)alloc((size_t)(N + 1) * 4);
  int*   degcur  = (int*)alloc((size_t)2 * N * 4);
  int*   deg     = degcur;
  int*   cursor  = degcur + N;
  int*   bsum    = (int*)alloc((size_t)NCHUNK * 4);
  int*   boff    = (int*)alloc((size_t)NCHUNK * 4);
  __hip_bfloat16* W1t     = (__hip_bfloat16*)alloc((size_t)NHID * NFEAT * 2);
  __hip_bfloat16* support = (__hip_bfloat16*)alloc((size_t)N * NHID * 2);
  float* h       = (float*)alloc((size_t)N * NHID * 4);
  __hip_bfloat16* s2 = (__hip_bfloat16*)alloc((size_t)N * NCLS * 2);

  // ---- CSR build (int atomics only) ----
  hipMemsetAsync(degcur, 0, (size_t)2 * N * 4, stream);
  hist_kernel<<<(E + 255) / 256, 256, 0, stream>>>(edst, deg, E);
  scan_part<<<NCHUNK, 256, 0, stream>>>(deg, bsum, N);
  scan_top<<<1, 1024, 0, stream>>>(bsum, boff, offs, NCHUNK, N);
  scan_apply<<<NCHUNK, 256, 0, stream>>>(deg, boff, offs, N);
  scatter_kernel<<<(E + 255) / 256, 256, 0, stream>>>(esrc, edst, ew, offs, cursor,
                                                      csrc, cw, E);

  // ---- layer 1 ----
  w1t_kernel<<<NFEAT / 64, 256, 0, stream>>>(W1, W1t);
  gemm1_mfma<<<(N + 63) / 64, 256, 0, stream>>>(x, W1t, support, N);
  spmm1_gather<<<(N + 3) / 4, 256, 0, stream>>>(offs, csrc, cw, support, b1, h, N);

  // ---- layer 2 ----
  gemm2_kernel<<<(N + 31) / 32, 256, 0, stream>>>(h, W2, s2, N);
  spmm2_gather<<<(N + 7) / 8, 256, 0, stream>>>(offs, csrc, cw, s2, b2, out, N);
}

// Round 6
// 228.407 us; speedup vs baseline: 8.7759x; 1.1119x over previous
//
#include <hip/hip_runtime.h>
#include <hip/hip_bf16.h>

// GCN forward: out = spmm(A, relu(spmm(A, x@W1)+b1) @ W2) + b2
// N=50000, F=512, H=128, C=40, E=800000
// Round 6: replace atomic scatter (82MB write-through, 66us) with two-pass
// bucket counting sort: LDS-grouped bucketize (coalesced flush) + per-bucket
// LDS-cursor scatter (L2-local packed int2 writes).

#define NFEAT 512
#define NHID  128
#define NCLS  40
#define BSH   8            // 256 dsts per bucket
#define ACHUNK 2048        // edges per bucketize block

typedef __attribute__((ext_vector_type(8))) short bf16x8;
typedef __attribute__((ext_vector_type(4))) short bf16x4;
typedef __attribute__((ext_vector_type(4))) float f32x4;

__device__ inline short f2bf(float f) {
  __hip_bfloat16 b = __float2bfloat16(f);
  return *reinterpret_cast<short*>(&b);
}

// ---------------- CSR build ----------------
__global__ __launch_bounds__(256) void hist_kernel(
    const int* __restrict__ edst, int* __restrict__ deg, int E) {
  int e = blockIdx.x * 256 + threadIdx.x;
  if (e < E) atomicAdd(&deg[edst[e]], 1);
}

__global__ __launch_bounds__(256) void scan_part(
    const int* __restrict__ deg, int* __restrict__ bsum, int n) {
  __shared__ int ws[4];
  int idx = blockIdx.x * 256 + threadIdx.x;
  int v = (idx < n) ? deg[idx] : 0;
#pragma unroll
  for (int o = 32; o > 0; o >>= 1) v += __shfl_down(v, o, 64);
  int lane = threadIdx.x & 63, w = threadIdx.x >> 6;
  if (lane == 0) ws[w] = v;
  __syncthreads();
  if (threadIdx.x == 0) bsum[blockIdx.x] = ws[0] + ws[1] + ws[2] + ws[3];
}

__global__ __launch_bounds__(1024) void scan_top(
    const int* __restrict__ bsum, int* __restrict__ boff,
    int* __restrict__ offs, int nchunk, int n) {
  __shared__ int part[1024];
  int tid = threadIdx.x;
  int v = (tid < nchunk) ? bsum[tid] : 0;
  part[tid] = v;
  __syncthreads();
  for (int o = 1; o < 1024; o <<= 1) {
    int t = (tid >= o) ? part[tid - o] : 0;
    __syncthreads();
    part[tid] += t;
    __syncthreads();
  }
  if (tid < nchunk) boff[tid] = part[tid] - v;
  if (tid == 0) offs[n] = part[nchunk - 1];
}

__global__ __launch_bounds__(256) void scan_apply(
    const int* __restrict__ deg, const int* __restrict__ boff,
    int* __restrict__ offs, int n) {
  __shared__ int part[256];
  int tid = threadIdx.x;
  int idx = blockIdx.x * 256 + tid;
  int v = (idx < n) ? deg[idx] : 0;
  part[tid] = v;
  __syncthreads();
  for (int o = 1; o < 256; o <<= 1) {
    int t = (tid >= o) ? part[tid - o] : 0;
    __syncthreads();
    part[tid] += t;
    __syncthreads();
  }
  if (idx < n) offs[idx] = boff[blockIdx.x] + part[tid] - v;
}

// bucket cursors init: bcur[b] = offs[b<<BSH]  (bucket = contiguous dst range,
// so its global CSR range is offs[d0]..offs[d0+256] -- no extra histogram)
__global__ __launch_bounds__(256) void init_bcur(
    const int* __restrict__ offs, int* __restrict__ bcur, int nb) {
  int t = blockIdx.x * 256 + threadIdx.x;
  if (t < nb) bcur[t] = offs[t << BSH];
}

// ---- pass A: bucketize edges with block-local LDS counting sort ----
__global__ __launch_bounds__(256) void bucketize(
    const int* __restrict__ esrc, const int* __restrict__ edst,
    const float* __restrict__ ew, int* __restrict__ bcur,
    int* __restrict__ bsrc, float* __restrict__ bw, int* __restrict__ bdst,
    int E, int nb) {
  __shared__ int lh[256], lo[256], gbase[256];
  __shared__ int s_src[ACHUNK];
  __shared__ float s_w[ACHUNK];
  __shared__ int s_dst[ACHUNK];
  const int tid = threadIdx.x;
  const int base = blockIdx.x * ACHUNK;
  const int cnt = min(ACHUNK, E - base);

  for (int t = tid; t < nb; t += 256) lh[t] = 0;
  __syncthreads();

  int my_s[8], my_d[8], my_t[8];
  float my_w[8];
#pragma unroll
  for (int i = 0; i < 8; ++i) {
    int idx = base + i * 256 + tid;
    if (idx < E) {
      my_s[i] = esrc[idx];
      my_d[i] = edst[idx];
      my_w[i] = ew[idx];
      my_t[i] = atomicAdd(&lh[my_d[i] >> BSH], 1);
    }
  }
  __syncthreads();
  if (tid == 0) {
    int run = 0;
    for (int b = 0; b < nb; ++b) { lo[b] = run; run += lh[b]; }
  }
  __syncthreads();
  if (tid < nb && lh[tid] > 0) gbase[tid] = atomicAdd(&bcur[tid], lh[tid]);
  __syncthreads();
#pragma unroll
  for (int i = 0; i < 8; ++i) {
    int idx = base + i * 256 + tid;
    if (idx < E) {
      int p = lo[my_d[i] >> BSH] + my_t[i];
      s_src[p] = my_s[i];
      s_w[p] = my_w[i];
      s_dst[p] = my_d[i];
    }
  }
  __syncthreads();
  // flush: bucket-contiguous in LDS -> contiguous global runs (coalesced)
  for (int j = tid; j < cnt; j += 256) {
    int d = s_dst[j];
    int b = d >> BSH;
    int g = gbase[b] + (j - lo[b]);
    bsrc[g] = s_src[j];
    bw[g] = s_w[j];
    bdst[g] = d;
  }
}

// ---- pass B: per-bucket final scatter, LDS cursors, packed int2 output ----
__global__ __launch_bounds__(256) void bucket_scatter(
    const int* __restrict__ offs, const int* __restrict__ bsrc,
    const float* __restrict__ bw, const int* __restrict__ bdst,
    int2* __restrict__ cwsrc, int n) {
  __shared__ int cur[1 << BSH];
  const int tid = threadIdx.x;
  const int d0 = blockIdx.x << BSH;
  const int nd = min(1 << BSH, n - d0);
  for (int t = tid; t < nd; t += 256) cur[t] = offs[d0 + t];
  __syncthreads();
  const int bstart = offs[d0];
  const int bend = offs[min(d0 + (1 << BSH), n)];
  for (int j = bstart + tid; j < bend; j += 256) {
    int d = bdst[j];
    int slot = atomicAdd(&cur[d - d0], 1);
    cwsrc[slot] = make_int2(bsrc[j], __float_as_int(bw[j]));
  }
}

// ---- W1 [512][128] f32 -> W1t [128][512] bf16 (transpose + convert) ----
__global__ __launch_bounds__(256) void w1t_kernel(
    const float* __restrict__ W1, __hip_bfloat16* __restrict__ W1t) {
  __shared__ float t[64][129];
  const int tid = threadIdx.x;
  const int k0 = blockIdx.x * 64;
#pragma unroll
  for (int i = 0; i < 8; ++i) {
    int f = i * 256 + tid;
    int r = f >> 5, c = (f & 31) << 2;
    float4 v = *(const float4*)&W1[(size_t)(k0 + r) * NHID + c];
    t[r][c] = v.x; t[r][c + 1] = v.y; t[r][c + 2] = v.z; t[r][c + 3] = v.w;
  }
  __syncthreads();
#pragma unroll
  for (int i = 0; i < 32; ++i) {
    int o = i * 256 + tid;
    int k = o & 63, n = o >> 6;
    W1t[(size_t)n * NFEAT + k0 + k] = __float2bfloat16(t[k][n]);
  }
}

// ---------- GEMM1 (MFMA): support[N,128] = bf16(x) @ bf16(W1), bf16 out ----------
__global__ __launch_bounds__(256) void gemm1_mfma(
    const float* __restrict__ x, const __hip_bfloat16* __restrict__ W1t,
    __hip_bfloat16* __restrict__ support, int nrows) {
  __shared__ __align__(16) char sA[2][64 * 64 * 2];
  __shared__ __align__(16) char sB[2][128 * 64 * 2];
  const int tid = threadIdx.x;
  const int lane = tid & 63;
  const int wid = tid >> 6;
  const int wm = wid >> 1, wn = wid & 1;
  const int row0 = blockIdx.x * 64;
  const int l15 = lane & 15, l4 = lane >> 4;

  f32x4 acc[2][4];
#pragma unroll
  for (int m = 0; m < 2; ++m)
#pragma unroll
    for (int n = 0; n < 4; ++n) acc[m][n] = (f32x4){0.f, 0.f, 0.f, 0.f};

  float4 ra[4];
  bf16x8 rb[4];

  auto LOADT = [&](int k0) {
#pragma unroll
    for (int i = 0; i < 4; ++i) {
      int f = i * 256 + tid;
      int r = f >> 4, c = (f & 15) << 2;
      int gr = row0 + r;
      float4 v = make_float4(0.f, 0.f, 0.f, 0.f);
      if (gr < nrows) v = *(const float4*)&x[(size_t)gr * NFEAT + k0 + c];
      ra[i] = v;
    }
#pragma unroll
    for (int i = 0; i < 4; ++i) {
      int f = i * 256 + tid;
      int r = f >> 3, c = (f & 7) << 3;
      rb[i] = *(const bf16x8*)&W1t[(size_t)r * NFEAT + k0 + c];
    }
  };
  auto WRITET = [&](int buf) {
#pragma unroll
    for (int i = 0; i < 4; ++i) {
      int f = i * 256 + tid;
      int r = f >> 4, c = (f & 15) << 2;
      bf16x4 s;
      s[0] = f2bf(ra[i].x); s[1] = f2bf(ra[i].y);
      s[2] = f2bf(ra[i].z); s[3] = f2bf(ra[i].w);
      int byte = (r * 128 + c * 2) ^ ((r & 7) << 4);
      *(bf16x4*)(sA[buf] + byte) = s;
    }
#pragma unroll
    for (int i = 0; i < 4; ++i) {
      int f = i * 256 + tid;
      int r = f >> 3, c = (f & 7) << 3;
      int byte = (r * 128 + c * 2) ^ ((r & 7) << 4);
      *(bf16x8*)(sB[buf] + byte) = rb[i];
    }
  };
  auto COMP = [&](int buf) {
#pragma unroll
    for (int kk = 0; kk < 64; kk += 32) {
      bf16x8 a[2], b[4];
      int cb = (kk + l4 * 8) * 2;
#pragma unroll
      for (int m = 0; m < 2; ++m) {
        int r = wm * 32 + m * 16 + l15;
        a[m] = *(const bf16x8*)(sA[buf] + ((r * 128 + cb) ^ ((r & 7) << 4)));
      }
#pragma unroll
      for (int n = 0; n < 4; ++n) {
        int r = wn * 64 + n * 16 + l15;
        b[n] = *(const bf16x8*)(sB[buf] + ((r * 128 + cb) ^ ((r & 7) << 4)));
      }
#pragma unroll
      for (int m = 0; m < 2; ++m)
#pragma unroll
        for (int n = 0; n < 4; ++n)
          acc[m][n] = __builtin_amdgcn_mfma_f32_16x16x32_bf16(a[m], b[n], acc[m][n], 0, 0, 0);
    }
  };

  LOADT(0);
  WRITET(0);
  __syncthreads();
  for (int t = 0; t < 8; ++t) {
    int cur = t & 1;
    if (t < 7) LOADT((t + 1) * 64);
    COMP(cur);
    if (t < 7) WRITET(cur ^ 1);
    __syncthreads();
  }

#pragma unroll
  for (int m = 0; m < 2; ++m) {
#pragma unroll
    for (int r = 0; r < 4; ++r) {
      int grow = row0 + wm * 32 + m * 16 + l4 * 4 + r;
      if (grow < nrows) {
#pragma unroll
        for (int n = 0; n < 4; ++n) {
          int col = wn * 64 + n * 16 + l15;
          support[(size_t)grow * NHID + col] = __float2bfloat16(acc[m][n][r]);
        }
      }
    }
  }
}

__device__ inline void bf2unpack(unsigned int u, float& lo, float& hi) {
  union { unsigned int ui; float f; } a, b;
  a.ui = (u & 0xffffu) << 16;
  b.ui = u & 0xffff0000u;
  lo = a.f; hi = b.f;
}

// ------- SpMM1 gather: h[n,f] = relu(b1[f] + sum_e w_e * support[src_e, f]) -------
__global__ __launch_bounds__(256) void spmm1_gather(
    const int* __restrict__ offs, const int2* __restrict__ cwsrc,
    const __hip_bfloat16* __restrict__ support,
    const float* __restrict__ b1, float* __restrict__ h, int n) {
  int node = blockIdx.x * 4 + (threadIdx.x >> 6);
  int f2 = threadIdx.x & 63;
  if (node >= n) return;
  int beg = offs[node], end = offs[node + 1];
  float a0 = 0.f, a1 = 0.f;
  const unsigned int* sp = (const unsigned int*)support;
  int i = beg;
  for (; i + 3 < end; i += 4) {
    int2 e0 = cwsrc[i], e1 = cwsrc[i + 1], e2 = cwsrc[i + 2], e3 = cwsrc[i + 3];
    unsigned int u0 = sp[(size_t)e0.x * 64 + f2];
    unsigned int u1 = sp[(size_t)e1.x * 64 + f2];
    unsigned int u2 = sp[(size_t)e2.x * 64 + f2];
    unsigned int u3 = sp[(size_t)e3.x * 64 + f2];
    float lo, hi;
    float w0 = __int_as_float(e0.y), w1 = __int_as_float(e1.y);
    float w2 = __int_as_float(e2.y), w3 = __int_as_float(e3.y);
    bf2unpack(u0, lo, hi); a0 += w0 * lo; a1 += w0 * hi;
    bf2unpack(u1, lo, hi); a0 += w1 * lo; a1 += w1 * hi;
    bf2unpack(u2, lo, hi); a0 += w2 * lo; a1 += w2 * hi;
    bf2unpack(u3, lo, hi); a0 += w3 * lo; a1 += w3 * hi;
  }
  for (; i < end; ++i) {
    int2 e = cwsrc[i];
    float w = __int_as_float(e.y);
    unsigned int u = sp[(size_t)e.x * 64 + f2];
    float lo, hi;
    bf2unpack(u, lo, hi);
    a0 += w * lo; a1 += w * hi;
  }
  float2 o;
  o.x = fmaxf(a0 + b1[f2 * 2], 0.f);
  o.y = fmaxf(a1 + b1[f2 * 2 + 1], 0.f);
  *(float2*)&h[(size_t)node * NHID + f2 * 2] = o;
}

// ------- GEMM2: s2[N,40] = h @ W2[128,40] -> bf16 out ------
__global__ __launch_bounds__(256) void gemm2_kernel(
    const float* __restrict__ h, const float* __restrict__ W2,
    __hip_bfloat16* __restrict__ s2, int nrows) {
  __shared__ float sh[32][128];
  __shared__ float swt[128][40];
  const int tid = threadIdx.x;
  for (int i = tid; i < 128 * 40; i += 256) swt[i / 40][i % 40] = W2[i];
  __syncthreads();
  const int row0 = blockIdx.x * 32;
#pragma unroll
  for (int i = 0; i < 4; ++i) {
    int f = tid + 256 * i;
    int r = f >> 5, c = (f & 31) << 2;
    int gr = row0 + r;
    float4 v = make_float4(0.f, 0.f, 0.f, 0.f);
    if (gr < nrows) v = *(const float4*)&h[(size_t)gr * NHID + c];
    sh[r][c] = v.x; sh[r][c + 1] = v.y; sh[r][c + 2] = v.z; sh[r][c + 3] = v.w;
  }
  __syncthreads();
#pragma unroll
  for (int j = 0; j < 5; ++j) {
    int o = tid + 256 * j;
    int r = o / 40, c = o % 40;
    float acc = 0.f;
#pragma unroll 8
    for (int k = 0; k < 128; ++k) acc += sh[r][k] * swt[k][c];
    int gr = row0 + r;
    if (gr < nrows) s2[(size_t)gr * NCLS + c] = __float2bfloat16(acc);
  }
}

// ------- SpMM2 gather: out[n,c] = b2[c] + sum_e w_e * s2[src_e, c] -------
__global__ __launch_bounds__(256) void spmm2_gather(
    const int* __restrict__ offs, const int2* __restrict__ cwsrc,
    const __hip_bfloat16* __restrict__ s2,
    const float* __restrict__ b2, float* __restrict__ out, int n) {
  int node = blockIdx.x * 8 + (threadIdx.x >> 5);
  int f2 = threadIdx.x & 31;
  if (node >= n || f2 >= 20) return;
  int beg = offs[node], end = offs[node + 1];
  float a0 = 0.f, a1 = 0.f;
  const unsigned int* sp = (const unsigned int*)s2;
  int i = beg;
  for (; i + 3 < end; i += 4) {
    int2 e0 = cwsrc[i], e1 = cwsrc[i + 1], e2 = cwsrc[i + 2], e3 = cwsrc[i + 3];
    unsigned int u0 = sp[(size_t)e0.x * 20 + f2];
    unsigned int u1 = sp[(size_t)e1.x * 20 + f2];
    unsigned int u2 = sp[(size_t)e2.x * 20 + f2];
    unsigned int u3 = sp[(size_t)e3.x * 20 + f2];
    float lo, hi;
    float w0 = __int_as_float(e0.y), w1 = __int_as_float(e1.y);
    float w2 = __int_as_float(e2.y), w3 = __int_as_float(e3.y);
    bf2unpack(u0, lo, hi); a0 += w0 * lo; a1 += w0 * hi;
    bf2unpack(u1, lo, hi); a0 += w1 * lo; a1 += w1 * hi;
    bf2unpack(u2, lo, hi); a0 += w2 * lo; a1 += w2 * hi;
    bf2unpack(u3, lo, hi); a0 += w3 * lo; a1 += w3 * hi;
  }
  for (; i < end; ++i) {
    int2 e = cwsrc[i];
    float w = __int_as_float(e.y);
    unsigned int u = sp[(size_t)e.x * 20 + f2];
    float lo, hi;
    bf2unpack(u, lo, hi);
    a0 += w * lo; a1 += w * hi;
  }
  float2 o;
  o.x = a0 + b2[f2 * 2];
  o.y = a1 + b2[f2 * 2 + 1];
  *(float2*)&out[(size_t)node * NCLS + f2 * 2] = o;
}

extern "C" void kernel_launch(void* const* d_in, const int* in_sizes, int n_in,
                              void* d_out, int out_size, void* d_ws, size_t ws_size,
                              hipStream_t stream) {
  const float* x   = (const float*)d_in[0];
  const float* W1  = (const float*)d_in[1];
  const float* b1  = (const float*)d_in[2];
  const float* W2  = (const float*)d_in[3];
  const float* b2  = (const float*)d_in[4];
  const int* esrc  = (const int*)d_in[5];
  const int* edst  = (const int*)d_in[6];
  const float* ew  = (const float*)d_in[7];
  float* out = (float*)d_out;

  const int N = in_sizes[0] / NFEAT;        // 50000
  const int E = in_sizes[5];                // 800000
  const int NCHUNK = (N + 255) / 256;       // 196
  const int NB = (N + (1 << BSH) - 1) >> BSH;  // 196 buckets

  char* ws = (char*)d_ws;
  size_t off = 0;
  auto alloc = [&](size_t bytes) {
    void* p = ws + off;
    off += (bytes + 255) & ~(size_t)255;
    return p;
  };
  int2*  cwsrc   = (int2*)alloc((size_t)E * 8);
  int*   offs    = (int*)alloc((size_t)(N + 1) * 4);
  int*   degcur  = (int*)alloc((size_t)N * 4);
  int*   deg     = degcur;
  int*   bsum    = (int*)alloc((size_t)NCHUNK * 4);
  int*   boff    = (int*)alloc((size_t)NCHUNK * 4);
  int*   bcur    = (int*)alloc((size_t)NB * 4);
  __hip_bfloat16* W1t     = (__hip_bfloat16*)alloc((size_t)NHID * NFEAT * 2);
  __hip_bfloat16* support = (__hip_bfloat16*)alloc((size_t)N * NHID * 2);
  float* h       = (float*)alloc((size_t)N * NHID * 4);
  __hip_bfloat16* s2 = (__hip_bfloat16*)alloc((size_t)N * NCLS * 2);
  // bucket arrays alias h (dead until spmm1, which runs after bucket_scatter)
  int*   bsrc = (int*)h;
  float* bw   = (float*)(h + E);
  int*   bdst = (int*)(h + 2 * (size_t)E);

  // ---- CSR build ----
  hipMemsetAsync(deg, 0, (size_t)N * 4, stream);
  hist_kernel<<<(E + 255) / 256, 256, 0, stream>>>(edst, deg, E);
  scan_part<<<NCHUNK, 256, 0, stream>>>(deg, bsum, N);
  scan_top<<<1, 1024, 0, stream>>>(bsum, boff, offs, NCHUNK, N);
  scan_apply<<<NCHUNK, 256, 0, stream>>>(deg, boff, offs, N);
  init_bcur<<<(NB + 255) / 256, 256, 0, stream>>>(offs, bcur, NB);
  bucketize<<<(E + ACHUNK - 1) / ACHUNK, 256, 0, stream>>>(
      esrc, edst, ew, bcur, bsrc, bw, bdst, E, NB);
  bucket_scatter<<<NB, 256, 0, stream>>>(offs, bsrc, bw, bdst, cwsrc, N);

  // ---- layer 1 ----
  w1t_kernel<<<NFEAT / 64, 256, 0, stream>>>(W1, W1t);
  gemm1_mfma<<<(N + 63) / 64, 256, 0, stream>>>(x, W1t, support, N);
  spmm1_gather<<<(N + 3) / 4, 256, 0, stream>>>(offs, cwsrc, support, b1, h, N);

  // ---- layer 2 ----
  gemm2_kernel<<<(N + 31) / 32, 256, 0, stream>>>(h, W2, s2, N);
  spmm2_gather<<<(N + 7) / 8, 256, 0, stream>>>(offs, cwsrc, s2, b2, out, N);
}